// Round 1
// baseline (251.498 us; speedup 1.0000x reference)
//
#include <hip/hip_runtime.h>

// SSIM loss: pred/target [16,3,512,512] fp32, 11x11 gaussian (sigma=1.5),
// zero-padded SAME depthwise conv, output scalar 1 - mean(ssim_map).
//
// Separable gaussian: horizontal pass then vertical pass over 5 quantities
// (p, t, p^2, t^2, p*t). Tile = 64 wide x 16 high per block, staged via LDS.

#define TW 64
#define TH 16
#define HR (TH + 10)   // 26 staged/hsum rows
#define SW (TW + 12)   // 76 staged cols (74 used + 2 pad)
#define IMG_H 512
#define IMG_W 512
#define NCHAN 48       // 16 * 3

// exp(-d^2/4.5) raw gaussian values, normalized at compile time
constexpr double RW1 = 0.8007374029168082;   // exp(-1/4.5)
constexpr double RW2 = 0.4111122905071876;   // exp(-4/4.5)
constexpr double RW3 = 0.1353352832366127;   // exp(-9/4.5)  = exp(-2)
constexpr double RW4 = 0.0285655007845504;   // exp(-16/4.5)
constexpr double RW5 = 0.0038659201394728;   // exp(-25/4.5)
constexpr double RSUM = 1.0 + 2.0 * (RW1 + RW2 + RW3 + RW4 + RW5);
constexpr float GW[11] = {
    (float)(RW5 / RSUM), (float)(RW4 / RSUM), (float)(RW3 / RSUM),
    (float)(RW2 / RSUM), (float)(RW1 / RSUM), (float)(1.0 / RSUM),
    (float)(RW1 / RSUM), (float)(RW2 / RSUM), (float)(RW3 / RSUM),
    (float)(RW4 / RSUM), (float)(RW5 / RSUM)};

__global__ __launch_bounds__(256, 3) void ssim_main(
    const float* __restrict__ pred, const float* __restrict__ tgt,
    double* __restrict__ ws) {
  __shared__ float sp[HR][SW];
  __shared__ float st[HR][SW];
  __shared__ float4 hs4[HR][TW];   // s1, s2, s11, s22
  __shared__ float  hs1[HR][TW];   // s12
  __shared__ float  wsum[4];

  const int tid = threadIdx.x;
  const int c0 = blockIdx.x * TW;
  const int r0 = blockIdx.y * TH;
  const int nc = blockIdx.z;
  const size_t base = (size_t)nc * IMG_H * IMG_W;
  const float* P = pred + base;
  const float* T = tgt + base;

  // ---- Phase A: stage raw tile + halo (zero-fill OOB: matches zero-pad conv)
  for (int j = tid; j < HR * SW; j += 256) {
    const int r = j / SW, cc = j % SW;
    const int gy = r0 - 5 + r, gx = c0 - 5 + cc;
    float vp = 0.f, vt = 0.f;
    if (gy >= 0 && gy < IMG_H && gx >= 0 && gx < IMG_W && cc < TW + 10) {
      const int gidx = gy * IMG_W + gx;
      vp = P[gidx];
      vt = T[gidx];
    }
    ((float*)sp)[j] = vp;
    ((float*)st)[j] = vt;
  }
  __syncthreads();

  // ---- Phase B: horizontal windowed sums of {p, t, p2, t2, pt}
  for (int j = tid; j < HR * TW; j += 256) {
    const int x = j & (TW - 1), r = j >> 6;
    float s1 = 0.f, s2 = 0.f, s11 = 0.f, s22 = 0.f, s12 = 0.f;
#pragma unroll
    for (int k = 0; k < 11; k++) {
      const float p = sp[r][x + k];
      const float t = st[r][x + k];
      const float w = GW[k];
      s1 += w * p;
      s2 += w * t;
      s11 += (w * p) * p;
      s22 += (w * t) * t;
      s12 += (w * p) * t;
    }
    hs4[r][x] = make_float4(s1, s2, s11, s22);
    hs1[r][x] = s12;
  }
  __syncthreads();

  // ---- Phase C: vertical windowed sums + SSIM map + local accumulate
  float lsum = 0.f;
  for (int j = tid; j < TH * TW; j += 256) {
    const int x = j & (TW - 1), r = j >> 6;
    float s1 = 0.f, s2 = 0.f, s11 = 0.f, s22 = 0.f, s12 = 0.f;
#pragma unroll
    for (int k = 0; k < 11; k++) {
      const float4 h = hs4[r + k][x];
      const float w = GW[k];
      s1 += w * h.x;
      s2 += w * h.y;
      s11 += w * h.z;
      s22 += w * h.w;
      s12 += w * hs1[r + k][x];
    }
    const float mu11 = s1 * s1;
    const float mu22 = s2 * s2;
    const float mu12 = s1 * s2;
    const float sig1 = s11 - mu11;
    const float sig2 = s22 - mu22;
    const float sig12 = s12 - mu12;
    const float C1v = 0.0001f;   // 0.01^2
    const float C2v = 0.0009f;   // 0.03^2
    const float num = (2.f * mu12 + C1v) * (2.f * sig12 + C2v);
    const float den = (mu11 + mu22 + C1v) * (sig1 + sig2 + C2v);
    lsum += num / den;
  }

  // ---- Block reduce, one f64 atomic per block into per-channel bucket
#pragma unroll
  for (int off = 32; off > 0; off >>= 1) lsum += __shfl_down(lsum, off, 64);
  if ((tid & 63) == 0) wsum[tid >> 6] = lsum;
  __syncthreads();
  if (tid == 0) {
    const float bsum = wsum[0] + wsum[1] + wsum[2] + wsum[3];
    unsafeAtomicAdd(&ws[nc], (double)bsum);
  }
}

__global__ void ssim_fin(const double* __restrict__ ws,
                         float* __restrict__ out) {
  const int l = threadIdx.x;
  double v = (l < NCHAN) ? ws[l] : 0.0;
#pragma unroll
  for (int off = 32; off > 0; off >>= 1) v += __shfl_down(v, off, 64);
  if (l == 0) out[0] = (float)(1.0 - v / (double)(IMG_H * IMG_W * NCHAN));
}

extern "C" void kernel_launch(void* const* d_in, const int* in_sizes, int n_in,
                              void* d_out, int out_size, void* d_ws,
                              size_t ws_size, hipStream_t stream) {
  const float* pred = (const float*)d_in[0];
  const float* tgt = (const float*)d_in[1];
  double* ws = (double*)d_ws;

  hipMemsetAsync(d_ws, 0, NCHAN * sizeof(double), stream);
  dim3 grid(IMG_W / TW, IMG_H / TH, NCHAN);
  ssim_main<<<grid, 256, 0, stream>>>(pred, tgt, ws);
  ssim_fin<<<1, 64, 0, stream>>>(ws, (float*)d_out);
}

// Round 2
// 196.059 us; speedup vs baseline: 1.2828x; 1.2828x over previous
//
#include <hip/hip_runtime.h>

// SSIM loss: pred/target [16,3,512,512] fp32, 11x11 gaussian (sigma=1.5),
// zero-padded SAME depthwise conv, output scalar 1 - mean(ssim_map).
//
// v2: separable conv, horizontal pass fused with global loads (register
// sliding window, 4 outputs/lane), vertical pass streams 18 hsum rows
// through registers (8 outputs/thread, 1 b128+1 b32 LDS read per row).
// Tile = 32 wide x 64 high. LDS = 47.4 KB -> 3 blocks/CU.

#define IMG 512
#define NCHAN 48
#define TW 32
#define TH 64
#define HR (TH + 10)   // 74 horizontal-sum rows per tile

// exp(-d^2/4.5) raw gaussian values, normalized at compile time
constexpr double RW1 = 0.8007374029168082;   // exp(-1/4.5)
constexpr double RW2 = 0.4111122905071876;   // exp(-4/4.5)
constexpr double RW3 = 0.1353352832366127;   // exp(-9/4.5)
constexpr double RW4 = 0.0285655007845504;   // exp(-16/4.5)
constexpr double RW5 = 0.0038659201394728;   // exp(-25/4.5)
constexpr double RSUM = 1.0 + 2.0 * (RW1 + RW2 + RW3 + RW4 + RW5);
constexpr float GW[11] = {
    (float)(RW5 / RSUM), (float)(RW4 / RSUM), (float)(RW3 / RSUM),
    (float)(RW2 / RSUM), (float)(RW1 / RSUM), (float)(1.0 / RSUM),
    (float)(RW1 / RSUM), (float)(RW2 / RSUM), (float)(RW3 / RSUM),
    (float)(RW4 / RSUM), (float)(RW5 / RSUM)};

__global__ __launch_bounds__(256, 3) void ssim_main(
    const float* __restrict__ pred, const float* __restrict__ tgt,
    double* __restrict__ ws) {
  __shared__ float4 hs4[HR][TW];   // s1, s2, s11, s22
  __shared__ float hs1[HR][TW];    // s12
  __shared__ float wsum[4];

  const int tid = threadIdx.x;
  const int c0 = blockIdx.x * TW;
  const int r0t = blockIdx.y * TH;
  const int nc = blockIdx.z;
  const size_t base = (size_t)nc * IMG * IMG;
  const float* __restrict__ P = pred + base;
  const float* __restrict__ T = tgt + base;

  // ---- Phase B: horizontal windowed sums, loads direct from global.
  // Lane layout: g = x-group (4 outputs), rb = row within iteration.
  {
    const int g = tid & 7;    // 8 groups * 4 = 32 cols
    const int rb = tid >> 3;  // 0..31 rows per iteration
    const int x0 = g * 4;
    const int gx0 = c0 + x0 - 8;  // aligned 20-float window start (mult of 4)
#pragma unroll
    for (int it = 0; it < 3; ++it) {
      const int h = it * 32 + rb;  // hsum row index 0..73
      if (h < HR) {
        const int gy = r0t - 5 + h;
        const bool rowok = (gy >= 0) && (gy < IMG);
        const float* __restrict__ Prow = P + (size_t)gy * IMG;
        const float* __restrict__ Trow = T + (size_t)gy * IMG;
        float pv[20], tv[20];
#pragma unroll
        for (int q = 0; q < 5; ++q) {
          const int gx = gx0 + q * 4;
          float4 vp = make_float4(0.f, 0.f, 0.f, 0.f);
          float4 vt = vp;
          // gx is a multiple of 4 and IMG%4==0: float4 is all-in or all-out.
          if (rowok && gx >= 0 && gx < IMG) {
            vp = *(const float4*)(Prow + gx);
            vt = *(const float4*)(Trow + gx);
          }
          pv[q * 4 + 0] = vp.x; pv[q * 4 + 1] = vp.y;
          pv[q * 4 + 2] = vp.z; pv[q * 4 + 3] = vp.w;
          tv[q * 4 + 0] = vt.x; tv[q * 4 + 1] = vt.y;
          tv[q * 4 + 2] = vt.z; tv[q * 4 + 3] = vt.w;
        }
#pragma unroll
        for (int o = 0; o < 4; ++o) {
          float s1 = 0.f, s2 = 0.f, s11 = 0.f, s22 = 0.f, s12 = 0.f;
#pragma unroll
          for (int k = 0; k < 11; ++k) {
            // output col x0+o, tap col x0+o-5+k -> window index 3+o+k
            const float p = pv[3 + o + k];
            const float t = tv[3 + o + k];
            const float w = GW[k];
            const float wp = w * p;
            const float wt = w * t;
            s1 += w * p;
            s2 += w * t;
            s11 += wp * p;
            s22 += wt * t;
            s12 += wp * t;
          }
          hs4[h][x0 + o] = make_float4(s1, s2, s11, s22);
          hs1[h][x0 + o] = s12;
        }
      }
    }
  }
  __syncthreads();

  // ---- Phase C: vertical windowed sums, row-streaming register reuse.
  // Thread owns column x, 8 consecutive output rows. Streams 18 hsum rows.
  float lsum = 0.f;
  {
    const int x = tid & (TW - 1);
    const int r0 = (tid >> 5) * 8;  // 8 row-groups * 8 = 64 rows
    float acc[8][5];
#pragma unroll
    for (int o = 0; o < 8; ++o)
#pragma unroll
      for (int q = 0; q < 5; ++q) acc[o][q] = 0.f;
#pragma unroll
    for (int j = 0; j < 18; ++j) {
      const float4 h4 = hs4[r0 + j][x];
      const float h1 = hs1[r0 + j][x];
#pragma unroll
      for (int o = 0; o < 8; ++o) {
        const int k = j - o;
        if (k >= 0 && k < 11) {
          const float w = GW[k];
          acc[o][0] += w * h4.x;
          acc[o][1] += w * h4.y;
          acc[o][2] += w * h4.z;
          acc[o][3] += w * h4.w;
          acc[o][4] += w * h1;
        }
      }
    }
#pragma unroll
    for (int o = 0; o < 8; ++o) {
      const float s1 = acc[o][0], s2 = acc[o][1];
      const float s11 = acc[o][2], s22 = acc[o][3], s12 = acc[o][4];
      const float mu11 = s1 * s1;
      const float mu22 = s2 * s2;
      const float mu12 = s1 * s2;
      const float num = (2.f * mu12 + 1e-4f) * (2.f * (s12 - mu12) + 9e-4f);
      const float den =
          (mu11 + mu22 + 1e-4f) * ((s11 - mu11) + (s22 - mu22) + 9e-4f);
      lsum += num * __builtin_amdgcn_rcpf(den);
    }
  }

  // ---- Block reduce, one f64 atomic per block into per-channel bucket
#pragma unroll
  for (int off = 32; off > 0; off >>= 1) lsum += __shfl_down(lsum, off, 64);
  if ((tid & 63) == 0) wsum[tid >> 6] = lsum;
  __syncthreads();
  if (tid == 0) {
    const float bsum = wsum[0] + wsum[1] + wsum[2] + wsum[3];
    unsafeAtomicAdd(&ws[nc], (double)bsum);
  }
}

__global__ void ssim_fin(const double* __restrict__ ws,
                         float* __restrict__ out) {
  const int l = threadIdx.x;
  double v = (l < NCHAN) ? ws[l] : 0.0;
#pragma unroll
  for (int off = 32; off > 0; off >>= 1) v += __shfl_down(v, off, 64);
  if (l == 0) out[0] = (float)(1.0 - v / (double)(IMG * IMG * NCHAN));
}

extern "C" void kernel_launch(void* const* d_in, const int* in_sizes, int n_in,
                              void* d_out, int out_size, void* d_ws,
                              size_t ws_size, hipStream_t stream) {
  const float* pred = (const float*)d_in[0];
  const float* tgt = (const float*)d_in[1];
  double* ws = (double*)d_ws;

  hipMemsetAsync(d_ws, 0, NCHAN * sizeof(double), stream);
  dim3 grid(IMG / TW, IMG / TH, NCHAN);
  ssim_main<<<grid, 256, 0, stream>>>(pred, tgt, ws);
  ssim_fin<<<1, 64, 0, stream>>>(ws, (float*)d_out);
}